// Round 18
// baseline (45.552 us; speedup 1.0000x reference)
//
#include <hip/hip_runtime.h>
#include <hip/hip_bf16.h>
#include <math.h>

#define D 40
#define DIN 128
#define S 2048
#define B 8
#define NROWS (B*S)   // 16384
#define DP 64         // padded depth for Q/K bf16 rows
#define XSTR 48       // xb row stride (ushorts)
#define PSTR 64       // pob row stride (ushorts, 128B = 2 aligned lines)
#define KSTR 72       // LDS K/V row stride (ushorts, 144B: 16B-aligned, 4-way banks)

typedef __bf16 bf16x8 __attribute__((ext_vector_type(8)));
typedef float f32x16 __attribute__((ext_vector_type(16)));

static __device__ __forceinline__ unsigned short f2bf(float f) {
    unsigned u = __builtin_bit_cast(unsigned, f);
    u += 0x7fff + ((u >> 16) & 1);   // RNE
    return (unsigned short)(u >> 16);
}
static __device__ __forceinline__ float bf2f(unsigned short h) {
    return __builtin_bit_cast(float, (unsigned)h << 16);
}
static __device__ __forceinline__ bf16x8 ldfrag(const unsigned short* p) {
    return __builtin_bit_cast(bf16x8, *(const uint4*)p);
}
static __device__ __forceinline__ unsigned cvtpk(float lo, float hi) {
    unsigned r;
    asm("v_cvt_pk_bf16_f32 %0, %1, %2" : "=v"(r) : "v"(lo), "v"(hi));
    return r;
}
static __device__ __forceinline__ void plswap(unsigned &a, unsigned &b) {
    asm("v_permlane32_swap_b32 %0, %1" : "+v"(a), "+v"(b));
}

// ---------------- Kernel 0: weight prep + bias table (fused) ----------------
__global__ __launch_bounds__(256) void k0_prep(
    const float* __restrict__ Wa, const float* __restrict__ ba, const float* __restrict__ ln1,
    const float* __restrict__ Wq, const float* __restrict__ Wk, const float* __restrict__ Wv,
    const float* __restrict__ Wo, const float* __restrict__ ln2,
    const float* __restrict__ wi, const float* __restrict__ wo,
    const float* __restrict__ rel_bias,
    unsigned short* __restrict__ waT, unsigned short* __restrict__ wqT,
    unsigned short* __restrict__ wkT, unsigned short* __restrict__ wvT,
    unsigned short* __restrict__ woT, unsigned short* __restrict__ wiT,
    unsigned short* __restrict__ wo2T, float* __restrict__ btab)
{
    int i = blockIdx.x * 256 + threadIdx.x;
    if (i < 64*144) {
        int col = i / 144, k = i - col*144;
        float v = 0.f;
        if (col < D) {
            if (k < DIN) v = Wa[k*D + col];
            else if (k == DIN) v = ba[col];
        }
        waT[i] = f2bf(v);
    }
    if (i < 64*48) {
        int col = i / 48, d = i - col*48;
        bool ok = (col < D && d < D);
        float s1 = ok ? ln1[d] : 0.f;
        float s2 = ok ? ln2[d] : 0.f;
        wqT[i]  = f2bf(ok ? Wq[d*D + col] * s1 : 0.f);
        wkT[i]  = f2bf(ok ? Wk[d*D + col] * s1 : 0.f);
        wvT[i]  = f2bf(ok ? Wv[d*D + col] * s1 : 0.f);
        woT[i]  = f2bf(ok ? Wo[d*D + col]      : 0.f);
        wiT[i]  = f2bf(ok ? wi[d*D + col] * s2 : 0.f);
        wo2T[i] = f2bf(ok ? wo[d*D + col]      : 0.f);
    }
    if (i < 2*S - 1) {
        int rel = i - (S - 1);          // rel = k - q
        int bucket = (rel > 0) ? 16 : 0;
        int ar = rel < 0 ? -rel : rel;
        int add;
        if (ar < 8) {
            add = ar;
        } else {
            float tt = logf((float)ar * 0.125f) / logf(16.0f) * 8.0f;
            int lg = 8 + (int)tt;
            add = lg < 15 ? lg : 15;
        }
        btab[i] = rel_bias[bucket + add];
    }
}

// Single-tile C-layout -> row-major bf16 frags (validated):
static __device__ __forceinline__ void repack1(const f32x16& t0, uint4& u0, uint4& u1)
{
    unsigned a0=cvtpk(t0[0],t0[1]),  a1=cvtpk(t0[2],t0[3]),
             a2=cvtpk(t0[4],t0[5]),  a3=cvtpk(t0[6],t0[7]);
    plswap(a0,a2); plswap(a1,a3);
    unsigned b0=cvtpk(t0[8],t0[9]),  b1=cvtpk(t0[10],t0[11]),
             b2=cvtpk(t0[12],t0[13]),b3=cvtpk(t0[14],t0[15]);
    plswap(b0,b2); plswap(b1,b3);
    u0 = (uint4){a0,a1,a2,a3}; u1 = (uint4){b0,b1,b2,b3};
}

// ---------------- Kernel 1: adapter + rmsnorm + QKV, all-MFMA, 2-wave col-split ----------------
__global__ __launch_bounds__(128) void k1_adapter_qkv(
    const float* __restrict__ embs,
    const unsigned short* __restrict__ waT, const unsigned short* __restrict__ wqT,
    const unsigned short* __restrict__ wkT, const unsigned short* __restrict__ wvT,
    unsigned short* __restrict__ xb, unsigned short* __restrict__ qb,
    unsigned short* __restrict__ kbq, unsigned short* __restrict__ vT)
{
    __shared__ __attribute__((aligned(16))) unsigned short sE16[32][136];
    __shared__ unsigned short sX[32][56];
    __shared__ float sSS[2][32];

    const int tid = threadIdx.x;

    {   // cooperative dense staging: thread -> (row = tid/4, 32-float chunk)
        int r = tid >> 2;
        int cc = (tid & 3) * 32;
        const float* src = embs + (size_t)(blockIdx.x*32 + r) * DIN + cc;
        #pragma unroll
        for (int i = 0; i < 4; ++i) {
            float4 f0 = *(const float4*)(src + i*8);
            float4 f1 = *(const float4*)(src + i*8 + 4);
            uint4 u = { cvtpk(f0.x, f0.y), cvtpk(f0.z, f0.w),
                        cvtpk(f1.x, f1.y), cvtpk(f1.z, f1.w) };
            *(uint4*)&sE16[r][cc + i*8] = u;
        }
    }
    __syncthreads();

    const int w   = tid >> 6;
    const int l   = tid & 63;
    const int lr  = l & 31, hi = l >> 5;
    const int row = blockIdx.x * 32 + lr;
    const int cb  = w * 32;

    bf16x8 eb[9];
    #pragma unroll
    for (int kk = 0; kk < 8; ++kk) eb[kk] = ldfrag(&sE16[lr][kk*16 + hi*8]);
    {
        uint4 u = { hi == 0 ? 0x3f80u : 0u, 0u, 0u, 0u };
        eb[8] = __builtin_bit_cast(bf16x8, u);
    }

    f32x16 x0 = {0,0,0,0,0,0,0,0,0,0,0,0,0,0,0,0};
    #pragma unroll
    for (int kk = 0; kk < 9; ++kk) {
        bf16x8 a0 = ldfrag(waT + (size_t)(cb + lr)*144 + kk*16 + hi*8);
        x0 = __builtin_amdgcn_mfma_f32_32x32x16_bf16(a0, eb[kk], x0, 0,0,0);
    }

    float ss = 0.f;
    #pragma unroll
    for (int r = 0; r < 16; ++r) {
        x0[r] = fmaxf(x0[r], 0.f);
        ss += x0[r]*x0[r];
    }
    ss += __shfl_xor(ss, 32);
    if (hi == 0) sSS[w][lr] = ss;
    __syncthreads();
    const float inv = rsqrtf((sSS[0][lr] + sSS[1][lr]) * (1.0f/D) + 1e-6f);

    {
        uint4 u0, u1; repack1(x0, u0, u1);
        unsigned short* p = xb + (size_t)row*XSTR;
        *(uint4*)(p + cb + hi*8) = u0;
        if (w == 0) *(uint4*)(p + 16 + hi*8) = u1;
    }

    f32x16 xh;
    #pragma unroll
    for (int r = 0; r < 16; ++r) xh[r] = x0[r] * inv;
    {
        uint4 u0, u1; repack1(xh, u0, u1);
        *(uint4*)(&sX[lr][cb + hi*8]) = u0;
        if (w == 0) *(uint4*)(&sX[lr][16 + hi*8]) = u1;
    }
    __syncthreads();
    bf16x8 hb[3];
    #pragma unroll
    for (int t = 0; t < 3; ++t) hb[t] = ldfrag(&sX[lr][t*16 + hi*8]);

    f32x16 qa={0,0,0,0,0,0,0,0,0,0,0,0,0,0,0,0};
    f32x16 ka={0,0,0,0,0,0,0,0,0,0,0,0,0,0,0,0};
    f32x16 va={0,0,0,0,0,0,0,0,0,0,0,0,0,0,0,0};
    #pragma unroll
    for (int t = 0; t < 3; ++t) {
        bf16x8 h = hb[t];
        qa = __builtin_amdgcn_mfma_f32_32x32x16_bf16(ldfrag(wqT + (size_t)(cb+lr)*48 + t*16 + hi*8), h, qa, 0,0,0);
        ka = __builtin_amdgcn_mfma_f32_32x32x16_bf16(ldfrag(wkT + (size_t)(cb+lr)*48 + t*16 + hi*8), h, ka, 0,0,0);
        va = __builtin_amdgcn_mfma_f32_32x32x16_bf16(ldfrag(wvT + (size_t)(cb+lr)*48 + t*16 + hi*8), h, va, 0,0,0);
    }

    {
        uint4 u0, u1; repack1(qa, u0, u1);
        unsigned short* p = qb + (size_t)row*DP;
        *(uint4*)(p + cb + hi*8) = u0;
        if (w == 0) *(uint4*)(p + 16 + hi*8) = u1;
    }
    {
        uint4 u0, u1; repack1(ka, u0, u1);
        unsigned short* p = kbq + (size_t)row*DP;
        *(uint4*)(p + cb + hi*8) = u0;
        if (w == 0) *(uint4*)(p + 16 + hi*8) = u1;
    }
    #pragma unroll
    for (int r = 0; r < 16; ++r) {
        int col = cb + (r&3) + 8*(r>>2) + 4*hi;
        vT[(size_t)col*NROWS + row] = f2bf(va[r]);
    }
}

// ---------------- Kernel 3: flash attention, LDS K/V + async-STAGE split (T14) ----------------
// Next chunk's global loads issue into registers BEFORE current chunk's compute
// (HBM/L2 latency hides under MFMA+exp); ds_write lands between the barriers.
__global__ __launch_bounds__(256) void k3_attn_mfma(
    const unsigned short* __restrict__ qb, const unsigned short* __restrict__ kb,
    const unsigned short* __restrict__ vT, const float* __restrict__ btab,
    unsigned short* __restrict__ pob, float* __restrict__ pl, int klen, int nsplit)
{
    __shared__ float sbtw[2176 + 16];
    __shared__ __attribute__((aligned(16))) unsigned short sK[64][KSTR];
    __shared__ __attribute__((aligned(16))) unsigned short sV[64][KSTR];

    const int q0blk = blockIdx.x * 128;
    const int kt0   = blockIdx.z * klen;
    const int woff  = (S-1) + kt0 - q0blk - 127;

    int tid = threadIdx.x;
    for (int i = tid; i < klen + 128; i += 256) {
        int g = woff + i;
        sbtw[i] = btab[g < 0 ? 0 : (g > 4094 ? 4094 : g)];
    }

    const int w  = tid >> 6, l = tid & 63;
    const int lr = l & 31,  hi = l >> 5;
    const int b  = blockIdx.y;
    const int q0 = q0blk + w * 32;

    const unsigned short* qrow = qb + ((size_t)(b*S) + q0 + lr) * DP + hi*8;
    bf16x8 qf0 = ldfrag(qrow);
    bf16x8 qf1 = ldfrag(qrow + 16);
    bf16x8 qf2 = ldfrag(qrow + 32);

    f32x16 of0 = {0,0,0,0,0,0,0,0,0,0,0,0,0,0,0,0};
    f32x16 of1 = {0,0,0,0,0,0,0,0,0,0,0,0,0,0,0,0};
    float el = 0.f;

    const int bb = 127 - w*32 - lr + 4*hi;

    const int srow = tid >> 3;          // 0..31
    const int scol = (tid & 7) * 8;     // ushort offset

    auto stageRegs = [&](int kc, uint4& rk0, uint4& rk1, uint4& rv0, uint4& rv1) {
        const unsigned short* src = kb + (size_t)(b*S + kt0 + kc)*DP;
        rk0 = *(const uint4*)(src + (size_t)srow*DP + scol);
        rk1 = *(const uint4*)(src + (size_t)(32 + srow)*DP + scol);
        const unsigned short* vsrc = vT + (size_t)(b*S) + kt0 + kc;
        rv0 = *(const uint4*)(vsrc + (size_t)srow*NROWS + scol);
        rv1 = *(const uint4*)(vsrc + (size_t)(32 + srow)*NROWS + scol);
    };
    auto writeLds = [&](const uint4& rk0, const uint4& rk1, const uint4& rv0, const uint4& rv1) {
        *(uint4*)&sK[srow][scol]      = rk0;
        *(uint4*)&sK[32 + srow][scol] = rk1;
        *(uint4*)&sV[srow][scol]      = rv0;
        *(uint4*)&sV[32 + srow][scol] = rv1;
    };

    auto compute = [&](int ktl, int kloc) {
        bf16x8 kf0 = ldfrag(&sK[kloc + lr][hi*8]);
        bf16x8 kf1 = ldfrag(&sK[kloc + lr][16 + hi*8]);
        bf16x8 kf2 = ldfrag(&sK[kloc + lr][32 + hi*8]);
        f32x16 c = {0,0,0,0,0,0,0,0,0,0,0,0,0,0,0,0};
        c = __builtin_amdgcn_mfma_f32_32x32x16_bf16(kf0, qf0, c, 0,0,0);
        c = __builtin_amdgcn_mfma_f32_32x32x16_bf16(kf1, qf1, c, 0,0,0);
        c = __builtin_amdgcn_mfma_f32_32x32x16_bf16(kf2, qf2, c, 0,0,0);

        float e[16];
        #pragma unroll
        for (int r = 0; r < 16; ++r) {
            float s = c[r] + sbtw[bb + ktl + (r&3) + 8*(r>>2)];
            e[r] = __expf(s);
            el += e[r];
        }
        unsigned a0 = cvtpk(e[0],  e[1]);
        unsigned a1 = cvtpk(e[2],  e[3]);
        unsigned a2 = cvtpk(e[4],  e[5]);
        unsigned a3 = cvtpk(e[6],  e[7]);
        plswap(a0, a2);
        plswap(a1, a3);
        unsigned b0 = cvtpk(e[8],  e[9]);
        unsigned b1 = cvtpk(e[10], e[11]);
        unsigned b2 = cvtpk(e[12], e[13]);
        unsigned b3 = cvtpk(e[14], e[15]);
        plswap(b0, b2);
        plswap(b1, b3);
        uint4 u0 = {a0, a1, a2, a3};
        uint4 u1 = {b0, b1, b2, b3};
        bf16x8 pa0 = __builtin_bit_cast(bf16x8, u0);
        bf16x8 pa1 = __builtin_bit_cast(bf16x8, u1);

        bf16x8 vf0 = ldfrag(&sV[lr][kloc + hi*8]);
        bf16x8 vf1 = ldfrag(&sV[lr][kloc + 16 + hi*8]);
        bf16x8 vf2 = ldfrag(&sV[32 + lr][kloc + hi*8]);
        bf16x8 vf3 = ldfrag(&sV[32 + lr][kloc + 16 + hi*8]);

        of0 = __builtin_amdgcn_mfma_f32_32x32x16_bf16(pa0, vf0, of0, 0,0,0);
        of0 = __builtin_amdgcn_mfma_f32_32x32x16_bf16(pa1, vf1, of0, 0,0,0);
        of1 = __builtin_amdgcn_mfma_f32_32x32x16_bf16(pa0, vf2, of1, 0,0,0);
        of1 = __builtin_amdgcn_mfma_f32_32x32x16_bf16(pa1, vf3, of1, 0,0,0);
    };

    {   // prologue: stage chunk 0
        uint4 rk0, rk1, rv0, rv1;
        stageRegs(0, rk0, rk1, rv0, rv1);
        writeLds(rk0, rk1, rv0, rv1);
    }
    __syncthreads();   // chunk0 + sbtw visible

    for (int kc = 0; kc < klen; kc += 64) {
        const bool more = (kc + 64 < klen);
        uint4 rk0, rk1, rv0, rv1;
        if (more) stageRegs(kc + 64, rk0, rk1, rv0, rv1);   // issue early: latency hides under compute
        compute(kc, 0);
        compute(kc + 32, 32);
        if (more) {
            __syncthreads();               // all reads of current chunk done
            writeLds(rk0, rk1, rv0, rv1);  // vmcnt wait folds in here
            __syncthreads();               // next chunk visible
        }
    }

    el += __shfl_xor(el, 32);

    // pob layout: [row][s], 128B rows
    const size_t rb0 = ((size_t)(b*S + q0) * nsplit + blockIdx.z);
    #pragma unroll
    for (int r = 0; r < 16; ++r) {
        int qr = (r&3) + 8*(r>>2) + 4*hi;
        unsigned short* pr = pob + (rb0 + (size_t)qr * nsplit) * PSTR;
        pr[lr] = f2bf(of0[r]);
        if (lr < 8) pr[32 + lr] = f2bf(of1[r]);
    }
    if (hi == 0) pl[(size_t)blockIdx.z * NROWS + b*S + q0 + lr] = el;
}

// ---------------- Kernel 4: combine + O-proj + residual + FF + rmsnorm, 2-wave col-split ----------------
__global__ __launch_bounds__(128) void k4_out_ff(
    const unsigned short* __restrict__ xb, const unsigned short* __restrict__ pob,
    const float* __restrict__ pl,
    const unsigned short* __restrict__ woT, const unsigned short* __restrict__ wiT,
    const unsigned short* __restrict__ wo2T, const float* __restrict__ lnf,
    float* __restrict__ out, int nsplit)
{
    __shared__ unsigned short sX[32][56];
    __shared__ float sSS[2][32];

    const int tid = threadIdx.x;
    const int w   = tid >> 6;
    const int l   = tid & 63;
    const int lr  = l & 31, hi = l >> 5;
    const int row = blockIdx.x * 32 + lr;
    const int cb  = w * 32;

    float lsum = 0.f;
    for (int s = 0; s < nsplit; ++s) lsum += pl[(size_t)s*NROWS + row];
    const float linv = 1.0f / lsum;

    float a[3][8];
    #pragma unroll
    for (int t = 0; t < 3; ++t)
        #pragma unroll
        for (int j = 0; j < 8; ++j) a[t][j] = 0.f;
    const unsigned short* prow = pob + (size_t)row * nsplit * PSTR;
    for (int s = 0; s < nsplit; ++s) {
        const unsigned short* pr = prow + (size_t)s * PSTR;
        #pragma unroll
        for (int t = 0; t < 3; ++t) {
            if (t == 2 && hi == 1) continue;          // d = 40..47 unwritten
            uint4 u = *(const uint4*)(pr + t*16 + hi*8);
            a[t][0] += bf2f((unsigned short)(u.x)); a[t][1] += bf2f((unsigned short)(u.x >> 16));
            a[t][2] += bf2f((unsigned short)(u.y)); a[t][3] += bf2f((unsigned short)(u.y >> 16));
            a[t][4] += bf2f((unsigned short)(u.z)); a[t][5] += bf2f((unsigned short)(u.z >> 16));
            a[t][6] += bf2f((unsigned short)(u.w)); a[t][7] += bf2f((unsigned short)(u.w >> 16));
        }
    }
    bf16x8 ab[3];
    #pragma unroll
    for (int t = 0; t < 3; ++t) {
        uint4 u = { cvtpk(a[t][0]*linv, a[t][1]*linv), cvtpk(a[t][2]*linv, a[t][3]*linv),
                    cvtpk(a[t][4]*linv, a[t][5]*linv), cvtpk(a[t][6]*linv, a[t][7]*linv) };
        ab[t] = __builtin_bit_cast(bf16x8, u);
    }

    f32x16 c = {0,0,0,0,0,0,0,0,0,0,0,0,0,0,0,0};
    #pragma unroll
    for (int t = 0; t < 3; ++t)
        c = __builtin_amdgcn_mfma_f32_32x32x16_bf16(ldfrag(woT + (size_t)(cb+lr)*48 + t*16 + hi*8), ab[t], c, 0,0,0);

    const unsigned short* xr = xb + (size_t)row*XSTR;
    if (w == 0) {
        #pragma unroll
        for (int rr = 0; rr < 4; ++rr) {
            ushort4 v = *(const ushort4*)(xr + rr*8 + 4*hi);
            c[rr*4+0] += bf2f(v.x); c[rr*4+1] += bf2f(v.y);
            c[rr*4+2] += bf2f(v.z); c[rr*4+3] += bf2f(v.w);
        }
    } else {
        ushort4 v = *(const ushort4*)(xr + 32 + 4*hi);
        c[0] += bf2f(v.x); c[1] += bf2f(v.y); c[2] += bf2f(v.z); c[3] += bf2f(v.w);
    }

    float ss = 0.f;
    #pragma unroll
    for (int r = 0; r < 16; ++r) ss += c[r]*c[r];
    ss += __shfl_xor(ss, 32);
    if (hi == 0) sSS[w][lr] = ss;
    __syncthreads();
    const float inv2 = rsqrtf((sSS[0][lr] + sSS[1][lr]) * (1.0f/D) + 1e-6f);

    f32x16 t0;
    #pragma unroll
    for (int r = 0; r < 16; ++r) t0[r] = c[r]*inv2;
    {
        uint4 u0, u1; repack1(t0, u0, u1);
        *(uint4*)(&sX[lr][cb + hi*8]) = u0;
        if (w == 0) *(uint4*)(&sX[lr][16 + hi*8]) = u1;
    }
    __syncthreads();
    bf16x8 hb[3];
    #pragma unroll
    for (int t = 0; t < 3; ++t) hb[t] = ldfrag(&sX[lr][t*16 + hi*8]);
    __syncthreads();

    f32x16 d = {0,0,0,0,0,0,0,0,0,0,0,0,0,0,0,0};
    #pragma unroll
    for (int t = 0; t < 3; ++t)
        d = __builtin_amdgcn_mfma_f32_32x32x16_bf16(ldfrag(wiT + (size_t)(cb+lr)*48 + t*16 + hi*8), hb[t], d, 0,0,0);
    #pragma unroll
    for (int r = 0; r < 16; ++r) d[r] = fmaxf(d[r], 0.f);
    {
        uint4 u0, u1; repack1(d, u0, u1);
        *(uint4*)(&sX[lr][cb + hi*8]) = u0;
        if (w == 0) *(uint4*)(&sX[lr][16 + hi*8]) = u1;
    }
    __syncthreads();
    bf16x8 fb[3];
    #pragma unroll
    for (int t = 0; t < 3; ++t) fb[t] = ldfrag(&sX[lr][t*16 + hi*8]);

    f32x16 e = {0,0,0,0,0,0,0,0,0,0,0,0,0,0,0,0};
    #pragma unroll
    for (int t = 0; t < 3; ++t)
        e = __builtin_amdgcn_mfma_f32_32x32x16_bf16(ldfrag(wo2T + (size_t)(cb+lr)*48 + t*16 + hi*8), fb[t], e, 0,0,0);
    #pragma unroll
    for (int r = 0; r < 16; ++r) e[r] += c[r];

    float ss2 = 0.f;
    #pragma unroll
    for (int r = 0; r < 16; ++r) ss2 += e[r]*e[r];
    ss2 += __shfl_xor(ss2, 32);
    if (hi == 0) sSS[w][lr] = ss2;
    __syncthreads();
    const float inv3 = rsqrtf((sSS[0][lr] + sSS[1][lr]) * (1.0f/D) + 1e-6f);

    float* orow = out + (size_t)row * D;
    if (w == 0) {
        #pragma unroll
        for (int rr = 0; rr < 4; ++rr) {
            float4 lf = *(const float4*)(lnf + rr*8 + 4*hi);
            float4 v = { e[rr*4+0]*inv3*lf.x, e[rr*4+1]*inv3*lf.y,
                         e[rr*4+2]*inv3*lf.z, e[rr*4+3]*inv3*lf.w };
            *(float4*)(orow + rr*8 + 4*hi) = v;
        }
    } else {
        float4 lf = *(const float4*)(lnf + 32 + 4*hi);
        float4 v = { e[0]*inv3*lf.x, e[1]*inv3*lf.y, e[2]*inv3*lf.z, e[3]*inv3*lf.w };
        *(float4*)(orow + 32 + 4*hi) = v;
    }
}

extern "C" void kernel_launch(void* const* d_in, const int* in_sizes, int n_in,
                              void* d_out, int out_size, void* d_ws, size_t ws_size,
                              hipStream_t stream) {
    const float* embs = (const float*)d_in[0];
    const float* Wa   = (const float*)d_in[1];
    const float* ba   = (const float*)d_in[2];
    const float* ln1  = (const float*)d_in[3];
    const float* Wq   = (const float*)d_in[4];
    const float* Wk   = (const float*)d_in[5];
    const float* Wv   = (const float*)d_in[6];
    const float* Wo   = (const float*)d_in[7];
    const float* ln2  = (const float*)d_in[8];
    const float* wi   = (const float*)d_in[9];
    const float* wo   = (const float*)d_in[10];
    const float* lnf  = (const float*)d_in[11];
    const float* rb   = (const float*)d_in[12];

    char* wsb = (char*)d_ws;
    unsigned short* xb   = (unsigned short*)(wsb);              // NROWS*48*2 = 1,572,864
    unsigned short* qb   = (unsigned short*)(wsb + 1572864);    // 2,097,152
    unsigned short* kbq  = (unsigned short*)(wsb + 3670016);    // 2,097,152
    unsigned short* vT   = (unsigned short*)(wsb + 5767168);    // 2,097,152
    unsigned short* waT  = (unsigned short*)(wsb + 7864320);    // 18,432
    unsigned short* wqT  = (unsigned short*)(wsb + 7882752);    // 6,144
    unsigned short* wkT  = (unsigned short*)(wsb + 7888896);
    unsigned short* wvT  = (unsigned short*)(wsb + 7895040);
    unsigned short* woT  = (unsigned short*)(wsb + 7901184);
    unsigned short* wiT  = (unsigned short*)(wsb + 7907328);
    unsigned short* wo2T = (unsigned short*)(wsb + 7913472);
    const size_t base = 7919616;

    int nsplit = 8;    // proven best
    while (nsplit > 1 &&
           base + (size_t)nsplit*(2097152 + 65536) + 16384 > ws_size)
        nsplit >>= 1;
    unsigned short* pob = (unsigned short*)(wsb + base);                     // NROWS*nsplit*PSTR*2
    float* pl   = (float*)(wsb + base + (size_t)nsplit*2097152);             // nsplit * NROWS*4
    float* btab = (float*)(wsb + base + (size_t)nsplit*(2097152 + 65536));   // 16,384
    int klen = S / nsplit;

    k0_prep<<<36, 256, 0, stream>>>(Wa, ba, ln1, Wq, Wk, Wv, Wo, ln2, wi, wo, rb,
                                    waT, wqT, wkT, wvT, woT, wiT, wo2T, btab);
    k1_adapter_qkv<<<NROWS/32, 128, 0, stream>>>(embs, waT, wqT, wkT, wvT, xb, qb, kbq, vT);
    k3_attn_mfma<<<dim3(S/128, B, nsplit), 256, 0, stream>>>(qb, kbq, vT, btab, pob, pl, klen, nsplit);
    k4_out_ff<<<NROWS/32, 128, 0, stream>>>(xb, pob, pl, woT, wiT, wo2T, lnf, (float*)d_out, nsplit);
}

// Round 20
// 44.864 us; speedup vs baseline: 1.0153x; 1.0153x over previous
//
#include <hip/hip_runtime.h>
#include <hip/hip_bf16.h>
#include <math.h>

#define D 40
#define DIN 128
#define S 2048
#define B 8
#define NROWS (B*S)   // 16384
#define DP 64         // padded depth for Q/K bf16 rows
#define XSTR 48       // xb row stride (ushorts)
#define PSTR 64       // pob row stride (ushorts, 128B = 2 aligned lines)
#define KSTR 72       // LDS K/V row stride (ushorts, 144B: 16B-aligned, 4-way banks)

typedef __bf16 bf16x8 __attribute__((ext_vector_type(8)));
typedef float f32x16 __attribute__((ext_vector_type(16)));

static __device__ __forceinline__ unsigned short f2bf(float f) {
    unsigned u = __builtin_bit_cast(unsigned, f);
    u += 0x7fff + ((u >> 16) & 1);   // RNE
    return (unsigned short)(u >> 16);
}
static __device__ __forceinline__ float bf2f(unsigned short h) {
    return __builtin_bit_cast(float, (unsigned)h << 16);
}
static __device__ __forceinline__ bf16x8 ldfrag(const unsigned short* p) {
    return __builtin_bit_cast(bf16x8, *(const uint4*)p);
}
static __device__ __forceinline__ unsigned cvtpk(float lo, float hi) {
    unsigned r;
    asm("v_cvt_pk_bf16_f32 %0, %1, %2" : "=v"(r) : "v"(lo), "v"(hi));
    return r;
}
static __device__ __forceinline__ void plswap(unsigned &a, unsigned &b) {
    asm("v_permlane32_swap_b32 %0, %1" : "+v"(a), "+v"(b));
}

// ---------------- Kernel 0: weight prep + bias table (fused) ----------------
__global__ __launch_bounds__(256) void k0_prep(
    const float* __restrict__ Wa, const float* __restrict__ ba, const float* __restrict__ ln1,
    const float* __restrict__ Wq, const float* __restrict__ Wk, const float* __restrict__ Wv,
    const float* __restrict__ Wo, const float* __restrict__ ln2,
    const float* __restrict__ wi, const float* __restrict__ wo,
    const float* __restrict__ rel_bias,
    unsigned short* __restrict__ waT, unsigned short* __restrict__ wqT,
    unsigned short* __restrict__ wkT, unsigned short* __restrict__ wvT,
    unsigned short* __restrict__ woT, unsigned short* __restrict__ wiT,
    unsigned short* __restrict__ wo2T, float* __restrict__ btab)
{
    int i = blockIdx.x * 256 + threadIdx.x;
    if (i < 64*144) {
        int col = i / 144, k = i - col*144;
        float v = 0.f;
        if (col < D) {
            if (k < DIN) v = Wa[k*D + col];
            else if (k == DIN) v = ba[col];
        }
        waT[i] = f2bf(v);
    }
    if (i < 64*48) {
        int col = i / 48, d = i - col*48;
        bool ok = (col < D && d < D);
        float s1 = ok ? ln1[d] : 0.f;
        float s2 = ok ? ln2[d] : 0.f;
        wqT[i]  = f2bf(ok ? Wq[d*D + col] * s1 : 0.f);
        wkT[i]  = f2bf(ok ? Wk[d*D + col] * s1 : 0.f);
        wvT[i]  = f2bf(ok ? Wv[d*D + col] * s1 : 0.f);
        woT[i]  = f2bf(ok ? Wo[d*D + col]      : 0.f);
        wiT[i]  = f2bf(ok ? wi[d*D + col] * s2 : 0.f);
        wo2T[i] = f2bf(ok ? wo[d*D + col]      : 0.f);
    }
    if (i < 2*S - 1) {
        int rel = i - (S - 1);          // rel = k - q
        int bucket = (rel > 0) ? 16 : 0;
        int ar = rel < 0 ? -rel : rel;
        int add;
        if (ar < 8) {
            add = ar;
        } else {
            float tt = logf((float)ar * 0.125f) / logf(16.0f) * 8.0f;
            int lg = 8 + (int)tt;
            add = lg < 15 ? lg : 15;
        }
        btab[i] = rel_bias[bucket + add];
    }
}

// Single-tile C-layout -> row-major bf16 frags (validated):
static __device__ __forceinline__ void repack1(const f32x16& t0, uint4& u0, uint4& u1)
{
    unsigned a0=cvtpk(t0[0],t0[1]),  a1=cvtpk(t0[2],t0[3]),
             a2=cvtpk(t0[4],t0[5]),  a3=cvtpk(t0[6],t0[7]);
    plswap(a0,a2); plswap(a1,a3);
    unsigned b0=cvtpk(t0[8],t0[9]),  b1=cvtpk(t0[10],t0[11]),
             b2=cvtpk(t0[12],t0[13]),b3=cvtpk(t0[14],t0[15]);
    plswap(b0,b2); plswap(b1,b3);
    u0 = (uint4){a0,a1,a2,a3}; u1 = (uint4){b0,b1,b2,b3};
}

// ---------------- Kernel 1: adapter + rmsnorm + QKV, all-MFMA, 2-wave col-split ----------------
__global__ __launch_bounds__(128) void k1_adapter_qkv(
    const float* __restrict__ embs,
    const unsigned short* __restrict__ waT, const unsigned short* __restrict__ wqT,
    const unsigned short* __restrict__ wkT, const unsigned short* __restrict__ wvT,
    unsigned short* __restrict__ xb, unsigned short* __restrict__ qb,
    unsigned short* __restrict__ kbq, unsigned short* __restrict__ vT)
{
    __shared__ __attribute__((aligned(16))) unsigned short sE16[32][136];
    __shared__ unsigned short sX[32][56];
    __shared__ float sSS[2][32];

    const int tid = threadIdx.x;

    {   // cooperative dense staging: thread -> (row = tid/4, 32-float chunk)
        int r = tid >> 2;
        int cc = (tid & 3) * 32;
        const float* src = embs + (size_t)(blockIdx.x*32 + r) * DIN + cc;
        #pragma unroll
        for (int i = 0; i < 4; ++i) {
            float4 f0 = *(const float4*)(src + i*8);
            float4 f1 = *(const float4*)(src + i*8 + 4);
            uint4 u = { cvtpk(f0.x, f0.y), cvtpk(f0.z, f0.w),
                        cvtpk(f1.x, f1.y), cvtpk(f1.z, f1.w) };
            *(uint4*)&sE16[r][cc + i*8] = u;
        }
    }
    __syncthreads();

    const int w   = tid >> 6;
    const int l   = tid & 63;
    const int lr  = l & 31, hi = l >> 5;
    const int row = blockIdx.x * 32 + lr;
    const int cb  = w * 32;

    bf16x8 eb[9];
    #pragma unroll
    for (int kk = 0; kk < 8; ++kk) eb[kk] = ldfrag(&sE16[lr][kk*16 + hi*8]);
    {
        uint4 u = { hi == 0 ? 0x3f80u : 0u, 0u, 0u, 0u };
        eb[8] = __builtin_bit_cast(bf16x8, u);
    }

    f32x16 x0 = {0,0,0,0,0,0,0,0,0,0,0,0,0,0,0,0};
    #pragma unroll
    for (int kk = 0; kk < 9; ++kk) {
        bf16x8 a0 = ldfrag(waT + (size_t)(cb + lr)*144 + kk*16 + hi*8);
        x0 = __builtin_amdgcn_mfma_f32_32x32x16_bf16(a0, eb[kk], x0, 0,0,0);
    }

    float ss = 0.f;
    #pragma unroll
    for (int r = 0; r < 16; ++r) {
        x0[r] = fmaxf(x0[r], 0.f);
        ss += x0[r]*x0[r];
    }
    ss += __shfl_xor(ss, 32);
    if (hi == 0) sSS[w][lr] = ss;
    __syncthreads();
    const float inv = rsqrtf((sSS[0][lr] + sSS[1][lr]) * (1.0f/D) + 1e-6f);

    {
        uint4 u0, u1; repack1(x0, u0, u1);
        unsigned short* p = xb + (size_t)row*XSTR;
        *(uint4*)(p + cb + hi*8) = u0;
        if (w == 0) *(uint4*)(p + 16 + hi*8) = u1;
    }

    f32x16 xh;
    #pragma unroll
    for (int r = 0; r < 16; ++r) xh[r] = x0[r] * inv;
    {
        uint4 u0, u1; repack1(xh, u0, u1);
        *(uint4*)(&sX[lr][cb + hi*8]) = u0;
        if (w == 0) *(uint4*)(&sX[lr][16 + hi*8]) = u1;
    }
    __syncthreads();
    bf16x8 hb[3];
    #pragma unroll
    for (int t = 0; t < 3; ++t) hb[t] = ldfrag(&sX[lr][t*16 + hi*8]);

    f32x16 qa={0,0,0,0,0,0,0,0,0,0,0,0,0,0,0,0};
    f32x16 ka={0,0,0,0,0,0,0,0,0,0,0,0,0,0,0,0};
    f32x16 va={0,0,0,0,0,0,0,0,0,0,0,0,0,0,0,0};
    #pragma unroll
    for (int t = 0; t < 3; ++t) {
        bf16x8 h = hb[t];
        qa = __builtin_amdgcn_mfma_f32_32x32x16_bf16(ldfrag(wqT + (size_t)(cb+lr)*48 + t*16 + hi*8), h, qa, 0,0,0);
        ka = __builtin_amdgcn_mfma_f32_32x32x16_bf16(ldfrag(wkT + (size_t)(cb+lr)*48 + t*16 + hi*8), h, ka, 0,0,0);
        va = __builtin_amdgcn_mfma_f32_32x32x16_bf16(ldfrag(wvT + (size_t)(cb+lr)*48 + t*16 + hi*8), h, va, 0,0,0);
    }

    {
        uint4 u0, u1; repack1(qa, u0, u1);
        unsigned short* p = qb + (size_t)row*DP;
        *(uint4*)(p + cb + hi*8) = u0;
        if (w == 0) *(uint4*)(p + 16 + hi*8) = u1;
    }
    {
        uint4 u0, u1; repack1(ka, u0, u1);
        unsigned short* p = kbq + (size_t)row*DP;
        *(uint4*)(p + cb + hi*8) = u0;
        if (w == 0) *(uint4*)(p + 16 + hi*8) = u1;
    }
    #pragma unroll
    for (int r = 0; r < 16; ++r) {
        int col = cb + (r&3) + 8*(r>>2) + 4*hi;
        vT[(size_t)col*NROWS + row] = f2bf(va[r]);
    }
}

// ---------------- Kernel 3: flash attention, 2 q-tiles per K/V stage ----------------
// Each block owns 256 q-rows (2 tiles of 128); each staged K/V chunk feeds both,
// halving total staging traffic and amortizing Q/bias/barrier overhead.
__global__ __launch_bounds__(256, 2) void k3_attn_mfma(
    const unsigned short* __restrict__ qb, const unsigned short* __restrict__ kb,
    const unsigned short* __restrict__ vT, const float* __restrict__ btab,
    unsigned short* __restrict__ pob, float* __restrict__ pl, int klen, int nsplit)
{
    __shared__ float sbtw[2432];
    __shared__ __attribute__((aligned(16))) unsigned short sK[64][KSTR];
    __shared__ __attribute__((aligned(16))) unsigned short sV[64][KSTR];

    const int q0blk = blockIdx.x * 256;
    const int kt0   = blockIdx.z * klen;
    const int woff  = (S-1) + kt0 - q0blk - 255;

    int tid = threadIdx.x;
    for (int i = tid; i < klen + 256; i += 256) {
        int g = woff + i;
        sbtw[i] = btab[g < 0 ? 0 : (g > 4094 ? 4094 : g)];
    }

    const int w  = tid >> 6, l = tid & 63;
    const int lr = l & 31,  hi = l >> 5;
    const int b  = blockIdx.y;
    const int q0a = q0blk + w * 32;
    const int q0b = q0a + 128;

    const unsigned short* qrA = qb + ((size_t)(b*S) + q0a + lr) * DP + hi*8;
    bf16x8 qfA[3] = { ldfrag(qrA), ldfrag(qrA + 16), ldfrag(qrA + 32) };
    const unsigned short* qrB = qb + ((size_t)(b*S) + q0b + lr) * DP + hi*8;
    bf16x8 qfB[3] = { ldfrag(qrB), ldfrag(qrB + 16), ldfrag(qrB + 32) };

    f32x16 oA0 = {0,0,0,0,0,0,0,0,0,0,0,0,0,0,0,0};
    f32x16 oA1 = {0,0,0,0,0,0,0,0,0,0,0,0,0,0,0,0};
    f32x16 oB0 = {0,0,0,0,0,0,0,0,0,0,0,0,0,0,0,0};
    f32x16 oB1 = {0,0,0,0,0,0,0,0,0,0,0,0,0,0,0,0};
    float elA = 0.f, elB = 0.f;

    const int bbA = 255 - w*32 - lr + 4*hi;
    const int bbB = bbA - 128;

    const int srow = tid >> 3;          // 0..31
    const int scol = (tid & 7) * 8;     // ushort offset

    auto stageRegs = [&](int kc, uint4& rk0, uint4& rk1, uint4& rv0, uint4& rv1) {
        const unsigned short* src = kb + (size_t)(b*S + kt0 + kc)*DP;
        rk0 = *(const uint4*)(src + (size_t)srow*DP + scol);
        rk1 = *(const uint4*)(src + (size_t)(32 + srow)*DP + scol);
        const unsigned short* vsrc = vT + (size_t)(b*S) + kt0 + kc;
        rv0 = *(const uint4*)(vsrc + (size_t)srow*NROWS + scol);
        rv1 = *(const uint4*)(vsrc + (size_t)(32 + srow)*NROWS + scol);
    };
    auto writeLds = [&](const uint4& rk0, const uint4& rk1, const uint4& rv0, const uint4& rv1) {
        *(uint4*)&sK[srow][scol]      = rk0;
        *(uint4*)&sK[32 + srow][scol] = rk1;
        *(uint4*)&sV[srow][scol]      = rv0;
        *(uint4*)&sV[32 + srow][scol] = rv1;
    };

    auto compute = [&](int ktl, int kloc, const bf16x8* qf,
                       f32x16& o0, f32x16& o1, float& el, int bb) {
        bf16x8 kf0 = ldfrag(&sK[kloc + lr][hi*8]);
        bf16x8 kf1 = ldfrag(&sK[kloc + lr][16 + hi*8]);
        bf16x8 kf2 = ldfrag(&sK[kloc + lr][32 + hi*8]);
        f32x16 c = {0,0,0,0,0,0,0,0,0,0,0,0,0,0,0,0};
        c = __builtin_amdgcn_mfma_f32_32x32x16_bf16(kf0, qf[0], c, 0,0,0);
        c = __builtin_amdgcn_mfma_f32_32x32x16_bf16(kf1, qf[1], c, 0,0,0);
        c = __builtin_amdgcn_mfma_f32_32x32x16_bf16(kf2, qf[2], c, 0,0,0);

        float e[16];
        #pragma unroll
        for (int r = 0; r < 16; ++r) {
            float s = c[r] + sbtw[bb + ktl + (r&3) + 8*(r>>2)];
            e[r] = __expf(s);
            el += e[r];
        }
        unsigned a0 = cvtpk(e[0],  e[1]);
        unsigned a1 = cvtpk(e[2],  e[3]);
        unsigned a2 = cvtpk(e[4],  e[5]);
        unsigned a3 = cvtpk(e[6],  e[7]);
        plswap(a0, a2);
        plswap(a1, a3);
        unsigned b0 = cvtpk(e[8],  e[9]);
        unsigned b1 = cvtpk(e[10], e[11]);
        unsigned b2 = cvtpk(e[12], e[13]);
        unsigned b3 = cvtpk(e[14], e[15]);
        plswap(b0, b2);
        plswap(b1, b3);
        uint4 u0 = {a0, a1, a2, a3};
        uint4 u1 = {b0, b1, b2, b3};
        bf16x8 pa0 = __builtin_bit_cast(bf16x8, u0);
        bf16x8 pa1 = __builtin_bit_cast(bf16x8, u1);

        bf16x8 vf0 = ldfrag(&sV[lr][kloc + hi*8]);
        bf16x8 vf1 = ldfrag(&sV[lr][kloc + 16 + hi*8]);
        bf16x8 vf2 = ldfrag(&sV[32 + lr][kloc + hi*8]);
        bf16x8 vf3 = ldfrag(&sV[32 + lr][kloc + 16 + hi*8]);

        o0 = __builtin_amdgcn_mfma_f32_32x32x16_bf16(pa0, vf0, o0, 0,0,0);
        o0 = __builtin_amdgcn_mfma_f32_32x32x16_bf16(pa1, vf1, o0, 0,0,0);
        o1 = __builtin_amdgcn_mfma_f32_32x32x16_bf16(pa0, vf2, o1, 0,0,0);
        o1 = __builtin_amdgcn_mfma_f32_32x32x16_bf16(pa1, vf3, o1, 0,0,0);
    };

    {   // prologue: stage chunk 0
        uint4 rk0, rk1, rv0, rv1;
        stageRegs(0, rk0, rk1, rv0, rv1);
        writeLds(rk0, rk1, rv0, rv1);
    }
    __syncthreads();   // chunk0 + sbtw visible

    for (int kc = 0; kc < klen; kc += 64) {
        const bool more = (kc + 64 < klen);
        uint4 rk0, rk1, rv0, rv1;
        if (more) stageRegs(kc + 64, rk0, rk1, rv0, rv1);
        compute(kc,      0,  qfA, oA0, oA1, elA, bbA);
        compute(kc,      0,  qfB, oB0, oB1, elB, bbB);
        compute(kc + 32, 32, qfA, oA0, oA1, elA, bbA);
        compute(kc + 32, 32, qfB, oB0, oB1, elB, bbB);
        if (more) {
            __syncthreads();
            writeLds(rk0, rk1, rv0, rv1);
            __syncthreads();
        }
    }

    elA += __shfl_xor(elA, 32);
    elB += __shfl_xor(elB, 32);

    // pob layout: [row][s], 128B rows
    const size_t rbA = ((size_t)(b*S + q0a) * nsplit + blockIdx.z);
    const size_t rbB = ((size_t)(b*S + q0b) * nsplit + blockIdx.z);
    #pragma unroll
    for (int r = 0; r < 16; ++r) {
        int qr = (r&3) + 8*(r>>2) + 4*hi;
        unsigned short* prA = pob + (rbA + (size_t)qr * nsplit) * PSTR;
        prA[lr] = f2bf(oA0[r]);
        if (lr < 8) prA[32 + lr] = f2bf(oA1[r]);
        unsigned short* prB = pob + (rbB + (size_t)qr * nsplit) * PSTR;
        prB[lr] = f2bf(oB0[r]);
        if (lr < 8) prB[32 + lr] = f2bf(oB1[r]);
    }
    if (hi == 0) {
        pl[(size_t)blockIdx.z * NROWS + b*S + q0a + lr] = elA;
        pl[(size_t)blockIdx.z * NROWS + b*S + q0b + lr] = elB;
    }
}

// ---------------- Kernel 4: combine + O-proj + residual + FF + rmsnorm, 2-wave col-split ----------------
__global__ __launch_bounds__(128) void k4_out_ff(
    const unsigned short* __restrict__ xb, const unsigned short* __restrict__ pob,
    const float* __restrict__ pl,
    const unsigned short* __restrict__ woT, const unsigned short* __restrict__ wiT,
    const unsigned short* __restrict__ wo2T, const float* __restrict__ lnf,
    float* __restrict__ out, int nsplit)
{
    __shared__ unsigned short sX[32][56];
    __shared__ float sSS[2][32];

    const int tid = threadIdx.x;
    const int w   = tid >> 6;
    const int l   = tid & 63;
    const int lr  = l & 31, hi = l >> 5;
    const int row = blockIdx.x * 32 + lr;
    const int cb  = w * 32;

    float lsum = 0.f;
    for (int s = 0; s < nsplit; ++s) lsum += pl[(size_t)s*NROWS + row];
    const float linv = 1.0f / lsum;

    float a[3][8];
    #pragma unroll
    for (int t = 0; t < 3; ++t)
        #pragma unroll
        for (int j = 0; j < 8; ++j) a[t][j] = 0.f;
    const unsigned short* prow = pob + (size_t)row * nsplit * PSTR;
    for (int s = 0; s < nsplit; ++s) {
        const unsigned short* pr = prow + (size_t)s * PSTR;
        #pragma unroll
        for (int t = 0; t < 3; ++t) {
            if (t == 2 && hi == 1) continue;          // d = 40..47 unwritten
            uint4 u = *(const uint4*)(pr + t*16 + hi*8);
            a[t][0] += bf2f((unsigned short)(u.x)); a[t][1] += bf2f((unsigned short)(u.x >> 16));
            a[t][2] += bf2f((unsigned short)(u.y)); a[t][3] += bf2f((unsigned short)(u.y >> 16));
            a[t][4] += bf2f((unsigned short)(u.z)); a[t][5] += bf2f((unsigned short)(u.z >> 16));
            a[t][6] += bf2f((unsigned short)(u.w)); a[t][7] += bf2f((unsigned short)(u.w >> 16));
        }
    }
    bf16x8 ab[3];
    #pragma unroll
    for (int t = 0; t < 3; ++t) {
        uint4 u = { cvtpk(a[t][0]*linv, a[t][1]*linv), cvtpk(a[t][2]*linv, a[t][3]*linv),
                    cvtpk(a[t][4]*linv, a[t][5]*linv), cvtpk(a[t][6]*linv, a[t][7]*linv) };
        ab[t] = __builtin_bit_cast(bf16x8, u);
    }

    f32x16 c = {0,0,0,0,0,0,0,0,0,0,0,0,0,0,0,0};
    #pragma unroll
    for (int t = 0; t < 3; ++t)
        c = __builtin_amdgcn_mfma_f32_32x32x16_bf16(ldfrag(woT + (size_t)(cb+lr)*48 + t*16 + hi*8), ab[t], c, 0,0,0);

    const unsigned short* xr = xb + (size_t)row*XSTR;
    if (w == 0) {
        #pragma unroll
        for (int rr = 0; rr < 4; ++rr) {
            ushort4 v = *(const ushort4*)(xr + rr*8 + 4*hi);
            c[rr*4+0] += bf2f(v.x); c[rr*4+1] += bf2f(v.y);
            c[rr*4+2] += bf2f(v.z); c[rr*4+3] += bf2f(v.w);
        }
    } else {
        ushort4 v = *(const ushort4*)(xr + 32 + 4*hi);
        c[0] += bf2f(v.x); c[1] += bf2f(v.y); c[2] += bf2f(v.z); c[3] += bf2f(v.w);
    }

    float ss = 0.f;
    #pragma unroll
    for (int r = 0; r < 16; ++r) ss += c[r]*c[r];
    ss += __shfl_xor(ss, 32);
    if (hi == 0) sSS[w][lr] = ss;
    __syncthreads();
    const float inv2 = rsqrtf((sSS[0][lr] + sSS[1][lr]) * (1.0f/D) + 1e-6f);

    f32x16 t0;
    #pragma unroll
    for (int r = 0; r < 16; ++r) t0[r] = c[r]*inv2;
    {
        uint4 u0, u1; repack1(t0, u0, u1);
        *(uint4*)(&sX[lr][cb + hi*8]) = u0;
        if (w == 0) *(uint4*)(&sX[lr][16 + hi*8]) = u1;
    }
    __syncthreads();
    bf16x8 hb[3];
    #pragma unroll
    for (int t = 0; t < 3; ++t) hb[t] = ldfrag(&sX[lr][t*16 + hi*8]);
    __syncthreads();

    f32x16 d = {0,0,0,0,0,0,0,0,0,0,0,0,0,0,0,0};
    #pragma unroll
    for (int t = 0; t < 3; ++t)
        d = __builtin_amdgcn_mfma_f32_32x32x16_bf16(ldfrag(wiT + (size_t)(cb+lr)*48 + t*16 + hi*8), hb[t], d, 0,0,0);
    #pragma unroll
    for (int r = 0; r < 16; ++r) d[r] = fmaxf(d[r], 0.f);
    {
        uint4 u0, u1; repack1(d, u0, u1);
        *(uint4*)(&sX[lr][cb + hi*8]) = u0;
        if (w == 0) *(uint4*)(&sX[lr][16 + hi*8]) = u1;
    }
    __syncthreads();
    bf16x8 fb[3];
    #pragma unroll
    for (int t = 0; t < 3; ++t) fb[t] = ldfrag(&sX[lr][t*16 + hi*8]);

    f32x16 e = {0,0,0,0,0,0,0,0,0,0,0,0,0,0,0,0};
    #pragma unroll
    for (int t = 0; t < 3; ++t)
        e = __builtin_amdgcn_mfma_f32_32x32x16_bf16(ldfrag(wo2T + (size_t)(cb+lr)*48 + t*16 + hi*8), fb[t], e, 0,0,0);
    #pragma unroll
    for (int r = 0; r < 16; ++r) e[r] += c[r];

    float ss2 = 0.f;
    #pragma unroll
    for (int r = 0; r < 16; ++r) ss2 += e[r]*e[r];
    ss2 += __shfl_xor(ss2, 32);
    if (hi == 0) sSS[w][lr] = ss2;
    __syncthreads();
    const float inv3 = rsqrtf((sSS[0][lr] + sSS[1][lr]) * (1.0f/D) + 1e-6f);

    float* orow = out + (size_t)row * D;
    if (w == 0) {
        #pragma unroll
        for (int rr = 0; rr < 4; ++rr) {
            float4 lf = *(const float4*)(lnf + rr*8 + 4*hi);
            float4 v = { e[rr*4+0]*inv3*lf.x, e[rr*4+1]*inv3*lf.y,
                         e[rr*4+2]*inv3*lf.z, e[rr*4+3]*inv3*lf.w };
            *(float4*)(orow + rr*8 + 4*hi) = v;
        }
    } else {
        float4 lf = *(const float4*)(lnf + 32 + 4*hi);
        float4 v = { e[0]*inv3*lf.x, e[1]*inv3*lf.y, e[2]*inv3*lf.z, e[3]*inv3*lf.w };
        *(float4*)(orow + 32 + 4*hi) = v;
    }
}

extern "C" void kernel_launch(void* const* d_in, const int* in_sizes, int n_in,
                              void* d_out, int out_size, void* d_ws, size_t ws_size,
                              hipStream_t stream) {
    const float* embs = (const float*)d_in[0];
    const float* Wa   = (const float*)d_in[1];
    const float* ba   = (const float*)d_in[2];
    const float* ln1  = (const float*)d_in[3];
    const float* Wq   = (const float*)d_in[4];
    const float* Wk   = (const float*)d_in[5];
    const float* Wv   = (const float*)d_in[6];
    const float* Wo   = (const float*)d_in[7];
    const float* ln2  = (const float*)d_in[8];
    const float* wi   = (const float*)d_in[9];
    const float* wo   = (const float*)d_in[10];
    const float* lnf  = (const float*)d_in[11];
    const float* rb   = (const float*)d_in[12];

    char* wsb = (char*)d_ws;
    unsigned short* xb   = (unsigned short*)(wsb);              // NROWS*48*2 = 1,572,864
    unsigned short* qb   = (unsigned short*)(wsb + 1572864);    // 2,097,152
    unsigned short* kbq  = (unsigned short*)(wsb + 3670016);    // 2,097,152
    unsigned short* vT   = (unsigned short*)(wsb + 5767168);    // 2,097,152
    unsigned short* waT  = (unsigned short*)(wsb + 7864320);    // 18,432
    unsigned short* wqT  = (unsigned short*)(wsb + 7882752);    // 6,144
    unsigned short* wkT  = (unsigned short*)(wsb + 7888896);
    unsigned short* wvT  = (unsigned short*)(wsb + 7895040);
    unsigned short* woT  = (unsigned short*)(wsb + 7901184);
    unsigned short* wiT  = (unsigned short*)(wsb + 7907328);
    unsigned short* wo2T = (unsigned short*)(wsb + 7913472);
    const size_t base = 7919616;

    int nsplit = 8;    // proven best
    while (nsplit > 1 &&
           base + (size_t)nsplit*(2097152 + 65536) + 16384 > ws_size)
        nsplit >>= 1;
    unsigned short* pob = (unsigned short*)(wsb + base);                     // NROWS*nsplit*PSTR*2
    float* pl   = (float*)(wsb + base + (size_t)nsplit*2097152);             // nsplit * NROWS*4
    float* btab = (float*)(wsb + base + (size_t)nsplit*(2097152 + 65536));   // 16,384
    int klen = S / nsplit;

    k0_prep<<<36, 256, 0, stream>>>(Wa, ba, ln1, Wq, Wk, Wv, Wo, ln2, wi, wo, rb,
                                    waT, wqT, wkT, wvT, woT, wiT, wo2T, btab);
    k1_adapter_qkv<<<NROWS/32, 128, 0, stream>>>(embs, waT, wqT, wkT, wvT, xb, qb, kbq, vT);
    k3_attn_mfma<<<dim3(S/256, B, nsplit), 256, 0, stream>>>(qb, kbq, vT, btab, pob, pl, klen, nsplit);
    k4_out_ff<<<NROWS/32, 128, 0, stream>>>(xb, pob, pl, woT, wiT, wo2T, lnf, (float*)d_out, nsplit);
}

// Round 23
// 43.093 us; speedup vs baseline: 1.0571x; 1.0411x over previous
//
#include <hip/hip_runtime.h>
#include <hip/hip_bf16.h>
#include <math.h>

#define D 40
#define DIN 128
#define S 2048
#define B 8
#define NROWS (B*S)   // 16384
#define DP 64         // padded depth for Q/K bf16 rows
#define XSTR 48       // xb row stride (ushorts)
#define PSTR 64       // pob row stride (ushorts; cols 40-41 carry el as f32 bits)
#define KSTR 72       // LDS K/V row stride (ushorts, 144B: 16B-aligned, 4-way banks)

typedef __bf16 bf16x8 __attribute__((ext_vector_type(8)));
typedef float f32x16 __attribute__((ext_vector_type(16)));

static __device__ __forceinline__ unsigned short f2bf(float f) {
    unsigned u = __builtin_bit_cast(unsigned, f);
    u += 0x7fff + ((u >> 16) & 1);   // RNE
    return (unsigned short)(u >> 16);
}
static __device__ __forceinline__ float bf2f(unsigned short h) {
    return __builtin_bit_cast(float, (unsigned)h << 16);
}
static __device__ __forceinline__ bf16x8 ldfrag(const unsigned short* p) {
    return __builtin_bit_cast(bf16x8, *(const uint4*)p);
}
static __device__ __forceinline__ unsigned cvtpk(float lo, float hi) {
    unsigned r;
    asm("v_cvt_pk_bf16_f32 %0, %1, %2" : "=v"(r) : "v"(lo), "v"(hi));
    return r;
}
static __device__ __forceinline__ void plswap(unsigned &a, unsigned &b) {
    asm("v_permlane32_swap_b32 %0, %1" : "+v"(a), "+v"(b));
}

// ---------------- Kernel 0: weight prep + bias table (fused) ----------------
__global__ __launch_bounds__(256) void k0_prep(
    const float* __restrict__ Wa, const float* __restrict__ ba, const float* __restrict__ ln1,
    const float* __restrict__ Wq, const float* __restrict__ Wk, const float* __restrict__ Wv,
    const float* __restrict__ Wo, const float* __restrict__ ln2,
    const float* __restrict__ wi, const float* __restrict__ wo,
    const float* __restrict__ rel_bias,
    unsigned short* __restrict__ waT, unsigned short* __restrict__ wqT,
    unsigned short* __restrict__ wkT, unsigned short* __restrict__ wvT,
    unsigned short* __restrict__ woT, unsigned short* __restrict__ wiT,
    unsigned short* __restrict__ wo2T, float* __restrict__ btab)
{
    int i = blockIdx.x * 256 + threadIdx.x;
    if (i < 64*144) {
        int col = i / 144, k = i - col*144;
        float v = 0.f;
        if (col < D) {
            if (k < DIN) v = Wa[k*D + col];
            else if (k == DIN) v = ba[col];
        }
        waT[i] = f2bf(v);
    }
    if (i < 64*48) {
        int col = i / 48, d = i - col*48;
        bool ok = (col < D && d < D);
        float s1 = ok ? ln1[d] : 0.f;
        float s2 = ok ? ln2[d] : 0.f;
        wqT[i]  = f2bf(ok ? Wq[d*D + col] * s1 : 0.f);
        wkT[i]  = f2bf(ok ? Wk[d*D + col] * s1 : 0.f);
        wvT[i]  = f2bf(ok ? Wv[d*D + col] * s1 : 0.f);
        woT[i]  = f2bf(ok ? Wo[d*D + col]      : 0.f);
        wiT[i]  = f2bf(ok ? wi[d*D + col] * s2 : 0.f);
        wo2T[i] = f2bf(ok ? wo[d*D + col]      : 0.f);
    }
    if (i < 2*S - 1) {
        int rel = i - (S - 1);          // rel = k - q
        int bucket = (rel > 0) ? 16 : 0;
        int ar = rel < 0 ? -rel : rel;
        int add;
        if (ar < 8) {
            add = ar;
        } else {
            float tt = logf((float)ar * 0.125f) / logf(16.0f) * 8.0f;
            int lg = 8 + (int)tt;
            add = lg < 15 ? lg : 15;
        }
        btab[i] = rel_bias[bucket + add];
    }
}

// Single-tile C-layout -> row-major bf16 frags (validated):
static __device__ __forceinline__ void repack1(const f32x16& t0, uint4& u0, uint4& u1)
{
    unsigned a0=cvtpk(t0[0],t0[1]),  a1=cvtpk(t0[2],t0[3]),
             a2=cvtpk(t0[4],t0[5]),  a3=cvtpk(t0[6],t0[7]);
    plswap(a0,a2); plswap(a1,a3);
    unsigned b0=cvtpk(t0[8],t0[9]),  b1=cvtpk(t0[10],t0[11]),
             b2=cvtpk(t0[12],t0[13]),b3=cvtpk(t0[14],t0[15]);
    plswap(b0,b2); plswap(b1,b3);
    u0 = (uint4){a0,a1,a2,a3}; u1 = (uint4){b0,b1,b2,b3};
}

// ---------------- Kernel 1: adapter + rmsnorm + QKV, all-MFMA, 2-wave col-split ----------------
__global__ __launch_bounds__(128) void k1_adapter_qkv(
    const float* __restrict__ embs,
    const unsigned short* __restrict__ waT, const unsigned short* __restrict__ wqT,
    const unsigned short* __restrict__ wkT, const unsigned short* __restrict__ wvT,
    unsigned short* __restrict__ xb, unsigned short* __restrict__ qb,
    unsigned short* __restrict__ kbq, unsigned short* __restrict__ vT)
{
    __shared__ __attribute__((aligned(16))) unsigned short sE16[32][136];
    __shared__ unsigned short sX[32][56];
    __shared__ float sSS[2][32];

    const int tid = threadIdx.x;

    {   // cooperative dense staging: thread -> (row = tid/4, 32-float chunk)
        int r = tid >> 2;
        int cc = (tid & 3) * 32;
        const float* src = embs + (size_t)(blockIdx.x*32 + r) * DIN + cc;
        #pragma unroll
        for (int i = 0; i < 4; ++i) {
            float4 f0 = *(const float4*)(src + i*8);
            float4 f1 = *(const float4*)(src + i*8 + 4);
            uint4 u = { cvtpk(f0.x, f0.y), cvtpk(f0.z, f0.w),
                        cvtpk(f1.x, f1.y), cvtpk(f1.z, f1.w) };
            *(uint4*)&sE16[r][cc + i*8] = u;
        }
    }
    __syncthreads();

    const int w   = tid >> 6;
    const int l   = tid & 63;
    const int lr  = l & 31, hi = l >> 5;
    const int row = blockIdx.x * 32 + lr;
    const int cb  = w * 32;

    bf16x8 eb[9];
    #pragma unroll
    for (int kk = 0; kk < 8; ++kk) eb[kk] = ldfrag(&sE16[lr][kk*16 + hi*8]);
    {
        uint4 u = { hi == 0 ? 0x3f80u : 0u, 0u, 0u, 0u };
        eb[8] = __builtin_bit_cast(bf16x8, u);
    }

    f32x16 x0 = {0,0,0,0,0,0,0,0,0,0,0,0,0,0,0,0};
    #pragma unroll
    for (int kk = 0; kk < 9; ++kk) {
        bf16x8 a0 = ldfrag(waT + (size_t)(cb + lr)*144 + kk*16 + hi*8);
        x0 = __builtin_amdgcn_mfma_f32_32x32x16_bf16(a0, eb[kk], x0, 0,0,0);
    }

    float ss = 0.f;
    #pragma unroll
    for (int r = 0; r < 16; ++r) {
        x0[r] = fmaxf(x0[r], 0.f);
        ss += x0[r]*x0[r];
    }
    ss += __shfl_xor(ss, 32);
    if (hi == 0) sSS[w][lr] = ss;
    __syncthreads();
    const float inv = rsqrtf((sSS[0][lr] + sSS[1][lr]) * (1.0f/D) + 1e-6f);

    {
        uint4 u0, u1; repack1(x0, u0, u1);
        unsigned short* p = xb + (size_t)row*XSTR;
        *(uint4*)(p + cb + hi*8) = u0;
        if (w == 0) *(uint4*)(p + 16 + hi*8) = u1;
    }

    f32x16 xh;
    #pragma unroll
    for (int r = 0; r < 16; ++r) xh[r] = x0[r] * inv;
    {
        uint4 u0, u1; repack1(xh, u0, u1);
        *(uint4*)(&sX[lr][cb + hi*8]) = u0;
        if (w == 0) *(uint4*)(&sX[lr][16 + hi*8]) = u1;
    }
    __syncthreads();
    bf16x8 hb[3];
    #pragma unroll
    for (int t = 0; t < 3; ++t) hb[t] = ldfrag(&sX[lr][t*16 + hi*8]);

    f32x16 qa={0,0,0,0,0,0,0,0,0,0,0,0,0,0,0,0};
    f32x16 ka={0,0,0,0,0,0,0,0,0,0,0,0,0,0,0,0};
    f32x16 va={0,0,0,0,0,0,0,0,0,0,0,0,0,0,0,0};
    #pragma unroll
    for (int t = 0; t < 3; ++t) {
        bf16x8 h = hb[t];
        qa = __builtin_amdgcn_mfma_f32_32x32x16_bf16(ldfrag(wqT + (size_t)(cb+lr)*48 + t*16 + hi*8), h, qa, 0,0,0);
        ka = __builtin_amdgcn_mfma_f32_32x32x16_bf16(ldfrag(wkT + (size_t)(cb+lr)*48 + t*16 + hi*8), h, ka, 0,0,0);
        va = __builtin_amdgcn_mfma_f32_32x32x16_bf16(ldfrag(wvT + (size_t)(cb+lr)*48 + t*16 + hi*8), h, va, 0,0,0);
    }

    {
        uint4 u0, u1; repack1(qa, u0, u1);
        unsigned short* p = qb + (size_t)row*DP;
        *(uint4*)(p + cb + hi*8) = u0;
        if (w == 0) *(uint4*)(p + 16 + hi*8) = u1;
    }
    {
        uint4 u0, u1; repack1(ka, u0, u1);
        unsigned short* p = kbq + (size_t)row*DP;
        *(uint4*)(p + cb + hi*8) = u0;
        if (w == 0) *(uint4*)(p + 16 + hi*8) = u1;
    }
    #pragma unroll
    for (int r = 0; r < 16; ++r) {
        int col = cb + (r&3) + 8*(r>>2) + 4*hi;
        vT[(size_t)col*NROWS + row] = f2bf(va[r]);
    }
}

// ---------------- Kernel 3: flash attention, 2 q-tiles/stage, double-buffered LDS ----------------
// One barrier per chunk (write into idle buffer after compute); el stored into
// pob cols 40-41 (f32 bits) so k4 needs no separate pl array.
__global__ __launch_bounds__(256, 2) void k3_attn_mfma(
    const unsigned short* __restrict__ qb, const unsigned short* __restrict__ kb,
    const unsigned short* __restrict__ vT, const float* __restrict__ btab,
    unsigned short* __restrict__ pob, int klen, int nsplit)
{
    __shared__ float sbtw[2432];
    __shared__ __attribute__((aligned(16))) unsigned short sK[2][64][KSTR];
    __shared__ __attribute__((aligned(16))) unsigned short sV[2][64][KSTR];

    const int q0blk = blockIdx.x * 256;
    const int kt0   = blockIdx.z * klen;
    const int woff  = (S-1) + kt0 - q0blk - 255;

    int tid = threadIdx.x;
    for (int i = tid; i < klen + 256; i += 256) {
        int g = woff + i;
        sbtw[i] = btab[g < 0 ? 0 : (g > 4094 ? 4094 : g)];
    }

    const int w  = tid >> 6, l = tid & 63;
    const int lr = l & 31,  hi = l >> 5;
    const int b  = blockIdx.y;
    const int q0a = q0blk + w * 32;
    const int q0b = q0a + 128;

    const unsigned short* qrA = qb + ((size_t)(b*S) + q0a + lr) * DP + hi*8;
    bf16x8 qfA[3] = { ldfrag(qrA), ldfrag(qrA + 16), ldfrag(qrA + 32) };
    const unsigned short* qrB = qb + ((size_t)(b*S) + q0b + lr) * DP + hi*8;
    bf16x8 qfB[3] = { ldfrag(qrB), ldfrag(qrB + 16), ldfrag(qrB + 32) };

    f32x16 oA0 = {0,0,0,0,0,0,0,0,0,0,0,0,0,0,0,0};
    f32x16 oA1 = {0,0,0,0,0,0,0,0,0,0,0,0,0,0,0,0};
    f32x16 oB0 = {0,0,0,0,0,0,0,0,0,0,0,0,0,0,0,0};
    f32x16 oB1 = {0,0,0,0,0,0,0,0,0,0,0,0,0,0,0,0};
    float elA = 0.f, elB = 0.f;

    const int bbA = 255 - w*32 - lr + 4*hi;
    const int bbB = bbA - 128;

    const int srow = tid >> 3;          // 0..31
    const int scol = (tid & 7) * 8;     // ushort offset

    auto stageRegs = [&](int kc, uint4& rk0, uint4& rk1, uint4& rv0, uint4& rv1) {
        const unsigned short* src = kb + (size_t)(b*S + kt0 + kc)*DP;
        rk0 = *(const uint4*)(src + (size_t)srow*DP + scol);
        rk1 = *(const uint4*)(src + (size_t)(32 + srow)*DP + scol);
        const unsigned short* vsrc = vT + (size_t)(b*S) + kt0 + kc;
        rv0 = *(const uint4*)(vsrc + (size_t)srow*NROWS + scol);
        rv1 = *(const uint4*)(vsrc + (size_t)(32 + srow)*NROWS + scol);
    };
    auto writeLds = [&](int bf, const uint4& rk0, const uint4& rk1, const uint4& rv0, const uint4& rv1) {
        *(uint4*)&sK[bf][srow][scol]      = rk0;
        *(uint4*)&sK[bf][32 + srow][scol] = rk1;
        *(uint4*)&sV[bf][srow][scol]      = rv0;
        *(uint4*)&sV[bf][32 + srow][scol] = rv1;
    };

    auto compute = [&](int ktl, int kloc, int bf, const bf16x8* qf,
                       f32x16& o0, f32x16& o1, float& el, int bb) {
        bf16x8 kf0 = ldfrag(&sK[bf][kloc + lr][hi*8]);
        bf16x8 kf1 = ldfrag(&sK[bf][kloc + lr][16 + hi*8]);
        bf16x8 kf2 = ldfrag(&sK[bf][kloc + lr][32 + hi*8]);
        f32x16 c = {0,0,0,0,0,0,0,0,0,0,0,0,0,0,0,0};
        c = __builtin_amdgcn_mfma_f32_32x32x16_bf16(kf0, qf[0], c, 0,0,0);
        c = __builtin_amdgcn_mfma_f32_32x32x16_bf16(kf1, qf[1], c, 0,0,0);
        c = __builtin_amdgcn_mfma_f32_32x32x16_bf16(kf2, qf[2], c, 0,0,0);

        float e[16];
        #pragma unroll
        for (int r = 0; r < 16; ++r) {
            float s = c[r] + sbtw[bb + ktl + (r&3) + 8*(r>>2)];
            e[r] = __expf(s);
            el += e[r];
        }
        unsigned a0 = cvtpk(e[0],  e[1]);
        unsigned a1 = cvtpk(e[2],  e[3]);
        unsigned a2 = cvtpk(e[4],  e[5]);
        unsigned a3 = cvtpk(e[6],  e[7]);
        plswap(a0, a2);
        plswap(a1, a3);
        unsigned b0 = cvtpk(e[8],  e[9]);
        unsigned b1 = cvtpk(e[10], e[11]);
        unsigned b2 = cvtpk(e[12], e[13]);
        unsigned b3 = cvtpk(e[14], e[15]);
        plswap(b0, b2);
        plswap(b1, b3);
        uint4 u0 = {a0, a1, a2, a3};
        uint4 u1 = {b0, b1, b2, b3};
        bf16x8 pa0 = __builtin_bit_cast(bf16x8, u0);
        bf16x8 pa1 = __builtin_bit_cast(bf16x8, u1);

        bf16x8 vf0 = ldfrag(&sV[bf][lr][kloc + hi*8]);
        bf16x8 vf1 = ldfrag(&sV[bf][lr][kloc + 16 + hi*8]);
        bf16x8 vf2 = ldfrag(&sV[bf][32 + lr][kloc + hi*8]);
        bf16x8 vf3 = ldfrag(&sV[bf][32 + lr][kloc + 16 + hi*8]);

        o0 = __builtin_amdgcn_mfma_f32_32x32x16_bf16(pa0, vf0, o0, 0,0,0);
        o0 = __builtin_amdgcn_mfma_f32_32x32x16_bf16(pa1, vf1, o0, 0,0,0);
        o1 = __builtin_amdgcn_mfma_f32_32x32x16_bf16(pa0, vf2, o1, 0,0,0);
        o1 = __builtin_amdgcn_mfma_f32_32x32x16_bf16(pa1, vf3, o1, 0,0,0);
    };

    {   // prologue: stage chunk 0 into buffer 0
        uint4 rk0, rk1, rv0, rv1;
        stageRegs(0, rk0, rk1, rv0, rv1);
        writeLds(0, rk0, rk1, rv0, rv1);
    }
    __syncthreads();   // chunk0 + sbtw visible

    int buf = 0;
    for (int kc = 0; kc < klen; kc += 64) {
        const bool more = (kc + 64 < klen);
        uint4 rk0, rk1, rv0, rv1;
        if (more) stageRegs(kc + 64, rk0, rk1, rv0, rv1);   // issue early (T14)
        compute(kc,      0,  buf, qfA, oA0, oA1, elA, bbA);
        compute(kc,      0,  buf, qfB, oB0, oB1, elB, bbB);
        compute(kc + 32, 32, buf, qfA, oA0, oA1, elA, bbA);
        compute(kc + 32, 32, buf, qfB, oB0, oB1, elB, bbB);
        if (more) {
            writeLds(buf ^ 1, rk0, rk1, rv0, rv1);  // idle buffer: no pre-barrier needed
            __syncthreads();                         // publish before next chunk reads
            buf ^= 1;
        }
    }

    elA += __shfl_xor(elA, 32);
    elB += __shfl_xor(elB, 32);

    // pob layout: [row][s], 128B rows; cols 40-41 carry el (f32 bits)
    const size_t rbA = ((size_t)(b*S + q0a) * nsplit + blockIdx.z);
    const size_t rbB = ((size_t)(b*S + q0b) * nsplit + blockIdx.z);
    #pragma unroll
    for (int r = 0; r < 16; ++r) {
        int qr = (r&3) + 8*(r>>2) + 4*hi;
        unsigned short* prA = pob + (rbA + (size_t)qr * nsplit) * PSTR;
        prA[lr] = f2bf(oA0[r]);
        if (lr < 8) prA[32 + lr] = f2bf(oA1[r]);
        unsigned short* prB = pob + (rbB + (size_t)qr * nsplit) * PSTR;
        prB[lr] = f2bf(oB0[r]);
        if (lr < 8) prB[32 + lr] = f2bf(oB1[r]);
    }
    if (hi == 0) {
        unsigned ea = __builtin_bit_cast(unsigned, elA);
        unsigned short* prA = pob + (rbA + (size_t)lr * nsplit) * PSTR;
        prA[40] = (unsigned short)ea; prA[41] = (unsigned short)(ea >> 16);
        unsigned eb2 = __builtin_bit_cast(unsigned, elB);
        unsigned short* prB = pob + (rbB + (size_t)lr * nsplit) * PSTR;
        prB[40] = (unsigned short)eb2; prB[41] = (unsigned short)(eb2 >> 16);
    }
}

// ---------------- Kernel 4: combine + O-proj + residual + FF + rmsnorm, 2-wave col-split ----------------
__global__ __launch_bounds__(128) void k4_out_ff(
    const unsigned short* __restrict__ xb, const unsigned short* __restrict__ pob,
    const unsigned short* __restrict__ woT, const unsigned short* __restrict__ wiT,
    const unsigned short* __restrict__ wo2T, const float* __restrict__ lnf,
    float* __restrict__ out, int nsplit)
{
    __shared__ unsigned short sX[32][56];
    __shared__ float sSS[2][32];

    const int tid = threadIdx.x;
    const int w   = tid >> 6;
    const int l   = tid & 63;
    const int lr  = l & 31, hi = l >> 5;
    const int row = blockIdx.x * 32 + lr;
    const int cb  = w * 32;

    // combine: pob[row][s], each 128B row carries partial O (cols 0-39) and el (cols 40-41)
    float lsum = 0.f;
    float a[3][8];
    #pragma unroll
    for (int t = 0; t < 3; ++t)
        #pragma unroll
        for (int j = 0; j < 8; ++j) a[t][j] = 0.f;
    const unsigned short* prow = pob + (size_t)row * nsplit * PSTR;
    for (int s = 0; s < nsplit; ++s) {
        const unsigned short* pr = prow + (size_t)s * PSTR;
        unsigned eu = (unsigned)pr[40] | ((unsigned)pr[41] << 16);
        lsum += __builtin_bit_cast(float, eu);
        #pragma unroll
        for (int t = 0; t < 3; ++t) {
            if (t == 2 && hi == 1) continue;          // d = 40..47 not O data
            uint4 u = *(const uint4*)(pr + t*16 + hi*8);
            a[t][0] += bf2f((unsigned short)(u.x)); a[t][1] += bf2f((unsigned short)(u.x >> 16));
            a[t][2] += bf2f((unsigned short)(u.y)); a[t][3] += bf2f((unsigned short)(u.y >> 16));
            a[t][4] += bf2f((unsigned short)(u.z)); a[t][5] += bf2f((unsigned short)(u.z >> 16));
            a[t][6] += bf2f((unsigned short)(u.w)); a[t][7] += bf2f((unsigned short)(u.w >> 16));
        }
    }
    const float linv = 1.0f / lsum;
    bf16x8 ab[3];
    #pragma unroll
    for (int t = 0; t < 3; ++t) {
        uint4 u = { cvtpk(a[t][0]*linv, a[t][1]*linv), cvtpk(a[t][2]*linv, a[t][3]*linv),
                    cvtpk(a[t][4]*linv, a[t][5]*linv), cvtpk(a[t][6]*linv, a[t][7]*linv) };
        ab[t] = __builtin_bit_cast(bf16x8, u);
    }

    f32x16 c = {0,0,0,0,0,0,0,0,0,0,0,0,0,0,0,0};
    #pragma unroll
    for (int t = 0; t < 3; ++t)
        c = __builtin_amdgcn_mfma_f32_32x32x16_bf16(ldfrag(woT + (size_t)(cb+lr)*48 + t*16 + hi*8), ab[t], c, 0,0,0);

    const unsigned short* xr = xb + (size_t)row*XSTR;
    if (w == 0) {
        #pragma unroll
        for (int rr = 0; rr < 4; ++rr) {
            ushort4 v = *(const ushort4*)(xr + rr*8 + 4*hi);
            c[rr*4+0] += bf2f(v.x); c[rr*4+1] += bf2f(v.y);
            c[rr*4+2] += bf2f(v.z); c[rr*4+3] += bf2f(v.w);
        }
    } else {
        ushort4 v = *(const ushort4*)(xr + 32 + 4*hi);
        c[0] += bf2f(v.x); c[1] += bf2f(v.y); c[2] += bf2f(v.z); c[3] += bf2f(v.w);
    }

    float ss = 0.f;
    #pragma unroll
    for (int r = 0; r < 16; ++r) ss += c[r]*c[r];
    ss += __shfl_xor(ss, 32);
    if (hi == 0) sSS[w][lr] = ss;
    __syncthreads();
    const float inv2 = rsqrtf((sSS[0][lr] + sSS[1][lr]) * (1.0f/D) + 1e-6f);

    f32x16 t0;
    #pragma unroll
    for (int r = 0; r < 16; ++r) t0[r] = c[r]*inv2;
    {
        uint4 u0, u1; repack1(t0, u0, u1);
        *(uint4*)(&sX[lr][cb + hi*8]) = u0;
        if (w == 0) *(uint4*)(&sX[lr][16 + hi*8]) = u1;
    }
    __syncthreads();
    bf16x8 hb[3];
    #pragma unroll
    for (int t = 0; t < 3; ++t) hb[t] = ldfrag(&sX[lr][t*16 + hi*8]);
    __syncthreads();

    f32x16 d = {0,0,0,0,0,0,0,0,0,0,0,0,0,0,0,0};
    #pragma unroll
    for (int t = 0; t < 3; ++t)
        d = __builtin_amdgcn_mfma_f32_32x32x16_bf16(ldfrag(wiT + (size_t)(cb+lr)*48 + t*16 + hi*8), hb[t], d, 0,0,0);
    #pragma unroll
    for (int r = 0; r < 16; ++r) d[r] = fmaxf(d[r], 0.f);
    {
        uint4 u0, u1; repack1(d, u0, u1);
        *(uint4*)(&sX[lr][cb + hi*8]) = u0;
        if (w == 0) *(uint4*)(&sX[lr][16 + hi*8]) = u1;
    }
    __syncthreads();
    bf16x8 fb[3];
    #pragma unroll
    for (int t = 0; t < 3; ++t) fb[t] = ldfrag(&sX[lr][t*16 + hi*8]);

    f32x16 e = {0,0,0,0,0,0,0,0,0,0,0,0,0,0,0,0};
    #pragma unroll
    for (int t = 0; t < 3; ++t)
        e = __builtin_amdgcn_mfma_f32_32x32x16_bf16(ldfrag(wo2T + (size_t)(cb+lr)*48 + t*16 + hi*8), fb[t], e, 0,0,0);
    #pragma unroll
    for (int r = 0; r < 16; ++r) e[r] += c[r];

    float ss2 = 0.f;
    #pragma unroll
    for (int r = 0; r < 16; ++r) ss2 += e[r]*e[r];
    ss2 += __shfl_xor(ss2, 32);
    if (hi == 0) sSS[w][lr] = ss2;
    __syncthreads();
    const float inv3 = rsqrtf((sSS[0][lr] + sSS[1][lr]) * (1.0f/D) + 1e-6f);

    float* orow = out + (size_t)row * D;
    if (w == 0) {
        #pragma unroll
        for (int rr = 0; rr < 4; ++rr) {
            float4 lf = *(const float4*)(lnf + rr*8 + 4*hi);
            float4 v = { e[rr*4+0]*inv3*lf.x, e[rr*4+1]*inv3*lf.y,
                         e[rr*4+2]*inv3*lf.z, e[rr*4+3]*inv3*lf.w };
            *(float4*)(orow + rr*8 + 4*hi) = v;
        }
    } else {
        float4 lf = *(const float4*)(lnf + 32 + 4*hi);
        float4 v = { e[0]*inv3*lf.x, e[1]*inv3*lf.y, e[2]*inv3*lf.z, e[3]*inv3*lf.w };
        *(float4*)(orow + 32 + 4*hi) = v;
    }
}

extern "C" void kernel_launch(void* const* d_in, const int* in_sizes, int n_in,
                              void* d_out, int out_size, void* d_ws, size_t ws_size,
                              hipStream_t stream) {
    const float* embs = (const float*)d_in[0];
    const float* Wa   = (const float*)d_in[1];
    const float* ba   = (const float*)d_in[2];
    const float* ln1  = (const float*)d_in[3];
    const float* Wq   = (const float*)d_in[4];
    const float* Wk   = (const float*)d_in[5];
    const float* Wv   = (const float*)d_in[6];
    const float* Wo   = (const float*)d_in[7];
    const float* ln2  = (const float*)d_in[8];
    const float* wi   = (const float*)d_in[9];
    const float* wo   = (const float*)d_in[10];
    const float* lnf  = (const float*)d_in[11];
    const float* rb   = (const float*)d_in[12];

    char* wsb = (char*)d_ws;
    unsigned short* xb   = (unsigned short*)(wsb);              // NROWS*48*2 = 1,572,864
    unsigned short* qb   = (unsigned short*)(wsb + 1572864);    // 2,097,152
    unsigned short* kbq  = (unsigned short*)(wsb + 3670016);    // 2,097,152
    unsigned short* vT   = (unsigned short*)(wsb + 5767168);    // 2,097,152
    unsigned short* waT  = (unsigned short*)(wsb + 7864320);    // 18,432
    unsigned short* wqT  = (unsigned short*)(wsb + 7882752);    // 6,144
    unsigned short* wkT  = (unsigned short*)(wsb + 7888896);
    unsigned short* wvT  = (unsigned short*)(wsb + 7895040);
    unsigned short* woT  = (unsigned short*)(wsb + 7901184);
    unsigned short* wiT  = (unsigned short*)(wsb + 7907328);
    unsigned short* wo2T = (unsigned short*)(wsb + 7913472);
    const size_t base = 7919616;

    int nsplit = 8;    // proven best
    while (nsplit > 1 &&
           base + (size_t)nsplit*2097152 + 16384 > ws_size)
        nsplit >>= 1;
    unsigned short* pob = (unsigned short*)(wsb + base);                     // NROWS*nsplit*PSTR*2
    float* btab = (float*)(wsb + base + (size_t)nsplit*2097152);             // 16,384
    int klen = S / nsplit;

    k0_prep<<<36, 256, 0, stream>>>(Wa, ba, ln1, Wq, Wk, Wv, Wo, ln2, wi, wo, rb,
                                    waT, wqT, wkT, wvT, woT, wiT, wo2T, btab);
    k1_adapter_qkv<<<NROWS/32, 128, 0, stream>>>(embs, waT, wqT, wkT, wvT, xb, qb, kbq, vT);
    k3_attn_mfma<<<dim3(S/256, B, nsplit), 256, 0, stream>>>(qb, kbq, vT, btab, pob, klen, nsplit);
    k4_out_ff<<<NROWS/32, 128, 0, stream>>>(xb, pob, woT, wiT, wo2T, lnf, (float*)d_out, nsplit);
}